// Round 7
// baseline (427.310 us; speedup 1.0000x reference)
//
#include <hip/hip_runtime.h>

#define BGRAPHS 512
#define FDIM    512
#define HDIM    256
#define NPG     256
#define KSEL    128
#define BSTAGE_SHORTS 8192         // 16 KB per stage of wsB: 2 planes * 8 nt * 64 lanes * 8 f16
#define A_ROW   24                 // A-plane row stride in shorts (16 + 8 pad, 16B-aligned rows)
#define A_PLANE (128 * A_ROW)      // 3072 shorts per plane (128 rows per block)
// K1 LDS: A only, 2 bufs * 2 planes * 6144 B = 24576 B. B comes straight from
// global (L1/L2-warm wsB) into VGPRs -> LDS read traffic halves, no vmcnt at
// barriers at all (lgkmcnt(0)-only barrier for the A double-buffer swap).
//
// ZERO-WORKSPACE layout (d_ws untouched; harness poison fill is unconditional
// but we keep the launch-count win):
//   wsB (512 KB)  -> mask output region. K0 writes -> K1 reads -> K2 overwrites.
//   scores stash  -> pooled region row g, cols 0..255 (self-overlap only).
//   loss          -> atomicAdd from K2 (zeroed by K0).

typedef __attribute__((ext_vector_type(8)))  _Float16 f16x8;
typedef __attribute__((ext_vector_type(8)))  short    s16x8;
typedef __attribute__((ext_vector_type(16))) float    f32x16;

// RNE float -> fp16 bits, also returns the fp16 value back as float
__device__ __forceinline__ unsigned short f16_rne(float f, float* back) {
    _Float16 h = (_Float16)f;          // v_cvt_f16_f32, RNE
    *back = (float)h;
    union { _Float16 h; unsigned short s; } cv; cv.h = h;
    return cv.s;
}

// ---------------------------------------------------------------------------
// K0: split W1 (fp32 [512][256], pre-scaled x1024) into 2 fp16 planes in MFMA
// B-fragment order for 16-k stages; destination is the mask output region.
// uid = ((s*2 + p)*8 + nt)*64 + lane, 8 f16 each,
// elem j = W1[s*16 + (lane>>5)*8 + j][nt*32 + (lane&31)]  (plane p), s in 0..31.
// Also zeroes the scalar loss output (accumulated atomically by K2).
// ---------------------------------------------------------------------------
__global__ __launch_bounds__(256)
void split_w1_kernel(const float* __restrict__ W1, unsigned short* __restrict__ wsB,
                     float* __restrict__ out_loss)
{
    if (blockIdx.x == 0 && threadIdx.x == 0) out_loss[0] = 0.f;

    const int uid  = blockIdx.x * 256 + threadIdx.x;     // 0..32767
    const int lane = uid & 63;
    int t = uid >> 6;
    const int nt = t & 7;  t >>= 3;
    const int p  = t & 1;  t >>= 1;
    const int s  = t;                                    // 0..31
    const int n  = nt * 32 + (lane & 31);
    const int k0 = s * 16 + (lane >> 5) * 8;

    s16x8 v;
    #pragma unroll
    for (int j = 0; j < 8; ++j) {
        float w = W1[(size_t)(k0 + j) * HDIM + n] * 1024.0f;   // B scale 2^10
        float f1, f2;
        unsigned short h1 = f16_rne(w, &f1);
        unsigned short h2 = f16_rne(w - f1, &f2);
        v[j] = (short)(p ? h2 : h1);
    }
    *(s16x8*)(wsB + (size_t)uid * 8) = v;
}

// ---------------------------------------------------------------------------
// K1 (GEMM+score): 1024 blocks = 2 per graph (row halves of 128), 512 thr =
// 8 waves (2 wy x 4 wx), wave tile 64x64, acc[2][2]. fp16 2-plane, 3 products
// (HH, MH, HM). A x2^6, B x2^10, unscale 2^-16.
// B fragments: per-wave global_load_dwordx4 from wsB (L1/L2-warm, perfectly
// coalesced 1KB/instr) -> VGPRs. A: converted in-kernel, LDS double-buffer,
// lgkmcnt(0)-only raw barrier per stage. No vmcnt at barriers.
// ---------------------------------------------------------------------------
__global__ __launch_bounds__(512, 4)
void gemm_kernel(const float* __restrict__ x,
                 const unsigned short* __restrict__ wsB,
                 const float* __restrict__ b1, const float* __restrict__ W2,
                 const float* __restrict__ b2,
                 float* __restrict__ scores_out)   // = pooled base, stride FDIM
{
    __shared__ __attribute__((aligned(16))) unsigned char smem[24576];

    const int bid  = blockIdx.x;
    const int g    = bid >> 1;
    const int rh   = bid & 1;         // row half: rows rh*128 .. rh*128+127
    const int tid  = threadIdx.x;
    const int lane = tid & 63;
    const int wv   = tid >> 6;        // 0..7
    const int wy   = wv & 1;          // row half-of-half (64 rows)
    const int wx   = wv >> 1;         // col quarter (64 cols)
    const int l31  = lane & 31;
    const int lh   = lane >> 5;
    const int nnB  = wx * 2;          // this wave's B nt base

    // A-staging ownership: thread owns 16B chunk (tid&3) of row (tid>>2)
    const int arow  = tid >> 2;       // 0..127
    const int achk  = tid & 3;        // 0..3
    const float* aptr = x + ((size_t)(g * NPG + rh * 128 + arow)) * FDIM + achk * 4;

    f32x16 acc[2][2];
    #pragma unroll
    for (int a = 0; a < 2; ++a)
        #pragma unroll
        for (int b = 0; b < 2; ++b)
            #pragma unroll
            for (int rr = 0; rr < 16; ++rr) acc[a][b][rr] = 0.f;

    float4 pfA, pfB;   // alternating x prefetch regs (even/odd target stages)

#define LOAD_PF(P,S2) do { P = *(const float4*)(aptr + (S2) * 16); } while (0)

#define CONVERT_A(P,BUF) do {                                                   \
    float _f[4] = {P.x, P.y, P.z, P.w};                                         \
    unsigned short _H[4], _M[4];                                                \
    _Pragma("unroll")                                                           \
    for (int _j = 0; _j < 4; ++_j) {                                            \
        float _b1v, _b2v;                                                       \
        float _xs = _f[_j] * 64.0f;      /* A scale 2^6 */                      \
        _H[_j] = f16_rne(_xs, &_b1v);                                           \
        _M[_j] = f16_rne(_xs - _b1v, &_b2v);                                    \
        (void)_b2v;                                                             \
    }                                                                           \
    unsigned short* _pl = (unsigned short*)(smem) + (BUF) * (2 * A_PLANE)       \
                          + arow * A_ROW + achk * 4;                            \
    uint2 _uH, _uM;                                                             \
    _uH.x = (unsigned)_H[0] | ((unsigned)_H[1] << 16);                          \
    _uH.y = (unsigned)_H[2] | ((unsigned)_H[3] << 16);                          \
    _uM.x = (unsigned)_M[0] | ((unsigned)_M[1] << 16);                          \
    _uM.y = (unsigned)_M[2] | ((unsigned)_M[3] << 16);                          \
    *(uint2*)_pl = _uH;                                                         \
    *(uint2*)(_pl + A_PLANE) = _uM;                                             \
    } while (0)

// B fragment (stage S, plane P, col J) straight from global: 1KB coalesced.
#define BFRAG(S,P,J) \
    (*(const f16x8*)(wsB + (size_t)((((S) * 2 + (P)) * 8 + nnB + (J)) * 64 + lane) * 8))

#define COMPUTE(S, ABUF) do {                                                   \
    f16x8 Bh0 = BFRAG(S, 0, 0);                                                 \
    f16x8 Bh1 = BFRAG(S, 0, 1);                                                 \
    f16x8 Bm0 = BFRAG(S, 1, 0);                                                 \
    f16x8 Bm1 = BFRAG(S, 1, 1);                                                 \
    const unsigned short* _aB = (const unsigned short*)(smem) + (ABUF) * (2 * A_PLANE); \
    const int _a0 = (wy * 64 + l31) * A_ROW + lh * 8;                           \
    f16x8 A0h = *(const f16x8*)(_aB + _a0);                                     \
    f16x8 A0m = *(const f16x8*)(_aB + A_PLANE + _a0);                           \
    f16x8 A1h = *(const f16x8*)(_aB + _a0 + 32 * A_ROW);                        \
    f16x8 A1m = *(const f16x8*)(_aB + A_PLANE + _a0 + 32 * A_ROW);              \
    acc[0][0] = __builtin_amdgcn_mfma_f32_32x32x16_f16(A0h, Bh0, acc[0][0], 0, 0, 0); \
    acc[0][1] = __builtin_amdgcn_mfma_f32_32x32x16_f16(A0h, Bh1, acc[0][1], 0, 0, 0); \
    acc[1][0] = __builtin_amdgcn_mfma_f32_32x32x16_f16(A1h, Bh0, acc[1][0], 0, 0, 0); \
    acc[1][1] = __builtin_amdgcn_mfma_f32_32x32x16_f16(A1h, Bh1, acc[1][1], 0, 0, 0); \
    acc[0][0] = __builtin_amdgcn_mfma_f32_32x32x16_f16(A0m, Bh0, acc[0][0], 0, 0, 0); \
    acc[0][1] = __builtin_amdgcn_mfma_f32_32x32x16_f16(A0m, Bh1, acc[0][1], 0, 0, 0); \
    acc[1][0] = __builtin_amdgcn_mfma_f32_32x32x16_f16(A1m, Bh0, acc[1][0], 0, 0, 0); \
    acc[1][1] = __builtin_amdgcn_mfma_f32_32x32x16_f16(A1m, Bh1, acc[1][1], 0, 0, 0); \
    acc[0][0] = __builtin_amdgcn_mfma_f32_32x32x16_f16(A0h, Bm0, acc[0][0], 0, 0, 0); \
    acc[0][1] = __builtin_amdgcn_mfma_f32_32x32x16_f16(A0h, Bm1, acc[0][1], 0, 0, 0); \
    acc[1][0] = __builtin_amdgcn_mfma_f32_32x32x16_f16(A1h, Bm0, acc[1][0], 0, 0, 0); \
    acc[1][1] = __builtin_amdgcn_mfma_f32_32x32x16_f16(A1h, Bm1, acc[1][1], 0, 0, 0); \
    } while (0)

// barrier for the A double-buffer swap only: all ds_read/ds_write retired
// (lgkmcnt counts both), then raw s_barrier. vmcnt stays untouched -> x/B
// loads in flight are never drained by a barrier.
#define SYNCL do {                                                              \
    asm volatile("s_waitcnt lgkmcnt(0)" ::: "memory");                          \
    __builtin_amdgcn_s_barrier();                                               \
    __builtin_amdgcn_sched_barrier(0); } while (0)

    // ---- prologue: convert x(0) -> buf0; prefetch x(1)
    LOAD_PF(pfA, 0);
    CONVERT_A(pfA, 0);
    LOAD_PF(pfB, 1);
    SYNCL;

    // ---- main K loop: stages 0..29, unrolled by 2
    for (int s = 0; s < 30; s += 2) {
        // even stage s: A-buf s&1=0; convert x(s+1)->buf1; prefetch x(s+2)
        LOAD_PF(pfA, s + 2);
        CONVERT_A(pfB, 1);
        COMPUTE(s, 0);
        SYNCL;

        // odd stage s+1: A-buf 1; convert x(s+2)->buf0; prefetch x(s+3)
        LOAD_PF(pfB, s + 3);
        CONVERT_A(pfA, 0);
        COMPUTE(s + 1, 1);
        SYNCL;
    }

    // ---- tail: stage 30 (convert x(31)->buf1), stage 31 (no convert)
    CONVERT_A(pfB, 1);
    COMPUTE(30, 0);
    SYNCL;
    COMPUTE(31, 1);

    // ---- epilogue: score = relu(h)*W2 summed over all 256 cols
    // scr (2 KB) overlays A-buf0 region: last read at stage 30, all waves
    // passed the SYNCL after stage 30 -> safe while stage-31 reads buf1.
    float* scr = (float*)smem;        // [4][128] partials per col-quarter

    float bb[2], ww[2];
    #pragma unroll
    for (int nt = 0; nt < 2; ++nt) {
        const int cc = wx * 64 + nt * 32 + l31;
        bb[nt] = b1[cc];
        ww[nt] = W2[cc];
    }
    const float unscale = 1.0f / 65536.0f;   // 2^-(6+10)
    #pragma unroll
    for (int mt = 0; mt < 2; ++mt) {
        float pr[16];
        #pragma unroll
        for (int rr = 0; rr < 16; ++rr) pr[rr] = 0.f;
        #pragma unroll
        for (int nt = 0; nt < 2; ++nt)
            #pragma unroll
            for (int rr = 0; rr < 16; ++rr) {
                float h = fmaf(acc[mt][nt][rr], unscale, bb[nt]);
                h = h > 0.f ? h : 0.f;
                pr[rr] = fmaf(h, ww[nt], pr[rr]);
            }
        #pragma unroll
        for (int mask = 1; mask <= 16; mask <<= 1)
            #pragma unroll
            for (int rr = 0; rr < 16; ++rr)
                pr[rr] += __shfl_xor(pr[rr], mask);
        if (l31 == 0) {
            #pragma unroll
            for (int rr = 0; rr < 16; ++rr) {
                const int row = wy * 64 + mt * 32 + (rr & 3) + 8 * (rr >> 2) + 4 * lh;
                scr[wx * 128 + row] = pr[rr];
            }
        }
    }
    __syncthreads();

    if (tid < 128) {
        const float s = b2[0] + scr[tid] + scr[128 + tid] + scr[256 + tid] + scr[384 + tid];
        scores_out[(size_t)g * FDIM + rh * 128 + tid] = s;   // interleaved stash
    }

#undef LOAD_PF
#undef CONVERT_A
#undef BFRAG
#undef COMPUTE
#undef SYNCL
}

// ---------------------------------------------------------------------------
// K2 (select + pool + loss): one block per graph, 512 threads. Reads graph g's
// scores from pooled row g (cols 0..255), barriers, then overwrites ONLY its
// own pooled row -> no cross-block race. Writes mask, atomically accumulates
// the margin loss into the scalar loss output.
// ---------------------------------------------------------------------------
__global__ __launch_bounds__(512)
void select_pool_kernel(const float* __restrict__ x,
                        float* __restrict__ pooled,      // scores stash in, pooled out
                        float* __restrict__ mask_out,
                        float* __restrict__ out_loss)
{
    __shared__ float sv[NPG];
    __shared__ int   selr[KSEL];
    __shared__ float redT[NPG];
    __shared__ float redS[NPG];

    const int g   = blockIdx.x;
    const int tid = threadIdx.x;

    float sc = 0.f;
    if (tid < NPG) {
        sc = pooled[(size_t)g * FDIM + tid];   // stashed scores, own row only
        sv[tid] = sc;
    }
    __syncthreads();

    // selection: exact rank (score desc, index asc on ties)
    if (tid < NPG) {
        int rank = 0;
        for (int j = 0; j < NPG; ++j) {
            const float sj = sv[j];
            rank += (sj > sc || (sj == sc && j < tid)) ? 1 : 0;
        }
        const bool sel = rank < KSEL;
        mask_out[g * NPG + tid] = sel ? 1.0f : 0.0f;
        if (sel) selr[rank] = tid;
        redT[tid] = sc;
        redS[tid] = sel ? sc : 0.f;
    }
    __syncthreads();

    for (int off = 128; off > 0; off >>= 1) {
        if (tid < off) { redT[tid] += redT[tid + off]; redS[tid] += redS[tid + off]; }
        __syncthreads();
    }
    if (tid == 0) {
        const float tot = redT[0], ssum = redS[0];
        const float sel_mean = ssum * (1.0f / KSEL);
        const float uns_mean = (tot - ssum) * (1.0f / (NPG - KSEL));
        const float v = 0.5f - (sel_mean - uns_mean);
        if (v > 0.f) atomicAdd(out_loss, v * (0.2f / BGRAPHS));
    }

    // pooled gather; col per thread, 8-way ILP; overwrites own row (scores
    // already consumed into sv/selr and all threads passed the barriers above)
    const int col = tid;
    const float* __restrict__ xg = x + (size_t)g * NPG * FDIM;
    float a0 = 0.f, a1 = 0.f, a2 = 0.f, a3 = 0.f;
    float a4 = 0.f, a5 = 0.f, a6 = 0.f, a7 = 0.f;
    #pragma unroll 2
    for (int n = 0; n < KSEL; n += 8) {
        a0 += xg[(size_t)selr[n + 0] * FDIM + col];
        a1 += xg[(size_t)selr[n + 1] * FDIM + col];
        a2 += xg[(size_t)selr[n + 2] * FDIM + col];
        a3 += xg[(size_t)selr[n + 3] * FDIM + col];
        a4 += xg[(size_t)selr[n + 4] * FDIM + col];
        a5 += xg[(size_t)selr[n + 5] * FDIM + col];
        a6 += xg[(size_t)selr[n + 6] * FDIM + col];
        a7 += xg[(size_t)selr[n + 7] * FDIM + col];
    }
    pooled[(size_t)g * FDIM + col] = ((a0 + a1) + (a2 + a3)) + ((a4 + a5) + (a6 + a7));
}

extern "C" void kernel_launch(void* const* d_in, const int* in_sizes, int n_in,
                              void* d_out, int out_size, void* d_ws, size_t ws_size,
                              hipStream_t stream)
{
    const float* x  = (const float*)d_in[0];
    const float* W1 = (const float*)d_in[2];
    const float* b1 = (const float*)d_in[3];
    const float* W2 = (const float*)d_in[4];
    const float* b2 = (const float*)d_in[5];

    float* out    = (float*)d_out;
    float* pooled = out;                       // [512*512] (also scores stash)
    float* loss   = out + BGRAPHS * FDIM;      // [1]      (atomic accumulator)
    float* mask   = loss + 1;                  // [131072] (also wsB home, 512 KB)

    unsigned short* wsB = (unsigned short*)mask;   // K0 -> K1 weight planes

    split_w1_kernel<<<128, 256, 0, stream>>>(W1, wsB, loss);
    gemm_kernel<<<2 * BGRAPHS, 512, 0, stream>>>(x, wsB, b1, W2, b2, pooled);
    select_pool_kernel<<<BGRAPHS, 512, 0, stream>>>(x, pooled, mask, loss);
}